// Round 1
// baseline (865.795 us; speedup 1.0000x reference)
//
#include <hip/hip_runtime.h>
#include <hip/hip_bf16.h>
#include <cstdint>

#define N_NODES 100000
#define N_EDGES 600000
#define C_IN    256
#define C_HID   128
#define C_OUT   128
#define LN_EPS  1e-5f
#define NEG_SLOPE 0.01f

#define TILE_M 64
#define KC     64

// ---- float <-> orderable-int (monotone map so int atomicMin == float min) ----
__device__ __forceinline__ int f2ord(float f) {
    int i = __float_as_int(f);
    return (i >= 0) ? i : (i ^ 0x7FFFFFFF);
}
__device__ __forceinline__ float ord2f(int o) {
    int i = (o >= 0) ? o : (o ^ 0x7FFFFFFF);
    return __int_as_float(i);
}

// +inf in orderable space == plain +inf bits (sentinel for "no edge wrote here")
#define ORD_INF 0x7F800000

// ---------------------------------------------------------------------------
// K0: init agg to orderable +inf  (ws is re-poisoned to 0xAA every launch)
// grid 12500 x 256, int4 per thread -> exactly N_NODES*C_HID ints
// ---------------------------------------------------------------------------
__global__ __launch_bounds__(256) void init_agg_kernel(int* __restrict__ agg) {
    int i = blockIdx.x * 256 + threadIdx.x;
    ((int4*)agg)[i] = make_int4(ORD_INF, ORD_INF, ORD_INF, ORD_INF);
}

// ---------------------------------------------------------------------------
// K1: h = LayerNorm(LeakyReLU(x @ W1 + b1))  -> h [N, 128] fp32 in ws
// block 256 = 8 row-groups x 32 col-threads; each thread: 8 rows x 4 cols.
// K staged in 64-wide chunks: sW 32KB + sX 17KB = 49KB LDS -> 3 blocks/CU.
// ---------------------------------------------------------------------------
__global__ __launch_bounds__(256) void gemm1_ln_kernel(
    const float* __restrict__ x, const float* __restrict__ W1,
    const float* __restrict__ b1, const float* __restrict__ gamma,
    const float* __restrict__ beta, float* __restrict__ h)
{
    __shared__ float sW[KC][C_HID];       // 32 KB, row-major chunk of W1
    __shared__ float sX[TILE_M][KC + 4];  // 17 KB, +4 pad (keeps rows 16B-mult)

    const int tid  = threadIdx.x;
    const int c    = tid & 31;   // cols 4c .. 4c+3
    const int g    = tid >> 5;   // row group: rows g*8 .. g*8+7
    const int row0 = blockIdx.x * TILE_M;

    float acc[8][4];
    #pragma unroll
    for (int i = 0; i < 8; ++i)
        #pragma unroll
        for (int j = 0; j < 4; ++j) acc[i][j] = 0.f;

    for (int k0 = 0; k0 < C_IN; k0 += KC) {
        // stage W1 chunk: 64x128 floats = 2048 float4, 8 per thread, coalesced
        #pragma unroll
        for (int l = 0; l < 8; ++l) {
            int idx = l * 256 + tid;
            int kk = idx >> 5, jj = idx & 31;
            ((float4*)&sW[kk][0])[jj] =
                ((const float4*)(W1 + (size_t)(k0 + kk) * C_HID))[jj];
        }
        // stage x tile: 64 rows x 64 k = 1024 float4, 4 per thread
        #pragma unroll
        for (int l = 0; l < 4; ++l) {
            int idx = l * 256 + tid;
            int r = idx >> 4, q = idx & 15;
            int grow = row0 + r;
            float4 v = make_float4(0.f, 0.f, 0.f, 0.f);
            if (grow < N_NODES)
                v = ((const float4*)(x + (size_t)grow * C_IN + k0))[q];
            ((float4*)&sX[r][0])[q] = v;
        }
        __syncthreads();

        for (int kk = 0; kk < KC; kk += 4) {
            // 4 cols of W for 4 consecutive k  (lanes c=0..31 contiguous 512B)
            float4 w0 = ((const float4*)&sW[kk + 0][0])[c];
            float4 w1v = ((const float4*)&sW[kk + 1][0])[c];
            float4 w2v = ((const float4*)&sW[kk + 2][0])[c];
            float4 w3v = ((const float4*)&sW[kk + 3][0])[c];
            #pragma unroll
            for (int i = 0; i < 8; ++i) {
                float4 xv = *((const float4*)&sX[g * 8 + i][kk]); // broadcast
                acc[i][0] += xv.x * w0.x + xv.y * w1v.x + xv.z * w2v.x + xv.w * w3v.x;
                acc[i][1] += xv.x * w0.y + xv.y * w1v.y + xv.z * w2v.y + xv.w * w3v.y;
                acc[i][2] += xv.x * w0.z + xv.y * w1v.z + xv.z * w2v.z + xv.w * w3v.z;
                acc[i][3] += xv.x * w0.w + xv.y * w1v.w + xv.z * w2v.w + xv.w * w3v.w;
            }
        }
        __syncthreads();
    }

    // epilogue: +b1, LeakyReLU, LayerNorm across the 32 lanes of this group
    const float4 b1v = ((const float4*)b1)[c];
    const float4 gv  = ((const float4*)gamma)[c];
    const float4 bv  = ((const float4*)beta)[c];

    #pragma unroll
    for (int i = 0; i < 8; ++i) {
        int grow = row0 + g * 8 + i;
        float v0 = acc[i][0] + b1v.x;
        float v1 = acc[i][1] + b1v.y;
        float v2 = acc[i][2] + b1v.z;
        float v3 = acc[i][3] + b1v.w;
        v0 = (v0 > 0.f) ? v0 : NEG_SLOPE * v0;
        v1 = (v1 > 0.f) ? v1 : NEG_SLOPE * v1;
        v2 = (v2 > 0.f) ? v2 : NEG_SLOPE * v2;
        v3 = (v3 > 0.f) ? v3 : NEG_SLOPE * v3;
        float s  = v0 + v1 + v2 + v3;
        float ss = v0 * v0 + v1 * v1 + v2 * v2 + v3 * v3;
        #pragma unroll
        for (int m = 1; m < 32; m <<= 1) {
            s  += __shfl_xor(s, m, 32);
            ss += __shfl_xor(ss, m, 32);
        }
        float mu   = s * (1.f / C_HID);
        float var  = ss * (1.f / C_HID) - mu * mu;
        float rstd = rsqrtf(var + LN_EPS);
        float4 o;
        o.x = (v0 - mu) * rstd * gv.x + bv.x;
        o.y = (v1 - mu) * rstd * gv.y + bv.y;
        o.z = (v2 - mu) * rstd * gv.z + bv.z;
        o.w = (v3 - mu) * rstd * gv.w + bv.w;
        if (grow < N_NODES)
            ((float4*)(h + (size_t)grow * C_HID))[c] = o;
    }
}

// ---------------------------------------------------------------------------
// K2: scatter-min. 32 threads per edge, 4 channels each.
// Stale-read prefilter is SAFE: agg only decreases, so observing cur <= h
// proves the true current value <= h and the atomic can be skipped.
// grid 75000 x 256 == 600000 edges * 32 threads exactly.
// ---------------------------------------------------------------------------
__global__ __launch_bounds__(256) void scatter_min_kernel(
    const int* __restrict__ ei, const float* __restrict__ h,
    int* __restrict__ agg)
{
    int t = blockIdx.x * 256 + threadIdx.x;
    int e = t >> 5;
    int c = t & 31;
    int src = ei[e];
    int dst = ei[N_EDGES + e];
    float4 hv = ((const float4*)(h + (size_t)src * C_HID))[c];
    int* a = agg + (size_t)dst * C_HID + c * 4;
    int4 cur = *((const int4*)a);
    int o0 = f2ord(hv.x), o1 = f2ord(hv.y), o2 = f2ord(hv.z), o3 = f2ord(hv.w);
    if (o0 < cur.x) atomicMin(a + 0, o0);
    if (o1 < cur.y) atomicMin(a + 1, o1);
    if (o2 < cur.z) atomicMin(a + 2, o2);
    if (o3 < cur.w) atomicMin(a + 3, o3);
}

// ---------------------------------------------------------------------------
// K3: out = agg @ W2 + b2, converting orderable-int -> float during staging
// (sentinel ORD_INF -> 0.0, matching PyG's empty-segment fill).
// Same tiling as K1, K = 128 in two 64-chunks.
// ---------------------------------------------------------------------------
__global__ __launch_bounds__(256) void gemm2_kernel(
    const int* __restrict__ agg, const float* __restrict__ W2,
    const float* __restrict__ b2, float* __restrict__ out)
{
    __shared__ float sW[KC][C_OUT];
    __shared__ float sX[TILE_M][KC + 4];

    const int tid  = threadIdx.x;
    const int c    = tid & 31;
    const int g    = tid >> 5;
    const int row0 = blockIdx.x * TILE_M;

    float acc[8][4];
    #pragma unroll
    for (int i = 0; i < 8; ++i)
        #pragma unroll
        for (int j = 0; j < 4; ++j) acc[i][j] = 0.f;

    for (int k0 = 0; k0 < C_HID; k0 += KC) {
        #pragma unroll
        for (int l = 0; l < 8; ++l) {
            int idx = l * 256 + tid;
            int kk = idx >> 5, jj = idx & 31;
            ((float4*)&sW[kk][0])[jj] =
                ((const float4*)(W2 + (size_t)(k0 + kk) * C_OUT))[jj];
        }
        #pragma unroll
        for (int l = 0; l < 4; ++l) {
            int idx = l * 256 + tid;
            int r = idx >> 4, q = idx & 15;
            int grow = row0 + r;
            float4 v = make_float4(0.f, 0.f, 0.f, 0.f);
            if (grow < N_NODES) {
                int4 iv = ((const int4*)(agg + (size_t)grow * C_HID + k0))[q];
                v.x = (iv.x == ORD_INF) ? 0.f : ord2f(iv.x);
                v.y = (iv.y == ORD_INF) ? 0.f : ord2f(iv.y);
                v.z = (iv.z == ORD_INF) ? 0.f : ord2f(iv.z);
                v.w = (iv.w == ORD_INF) ? 0.f : ord2f(iv.w);
            }
            ((float4*)&sX[r][0])[q] = v;
        }
        __syncthreads();

        for (int kk = 0; kk < KC; kk += 4) {
            float4 w0 = ((const float4*)&sW[kk + 0][0])[c];
            float4 w1v = ((const float4*)&sW[kk + 1][0])[c];
            float4 w2v = ((const float4*)&sW[kk + 2][0])[c];
            float4 w3v = ((const float4*)&sW[kk + 3][0])[c];
            #pragma unroll
            for (int i = 0; i < 8; ++i) {
                float4 xv = *((const float4*)&sX[g * 8 + i][kk]);
                acc[i][0] += xv.x * w0.x + xv.y * w1v.x + xv.z * w2v.x + xv.w * w3v.x;
                acc[i][1] += xv.x * w0.y + xv.y * w1v.y + xv.z * w2v.y + xv.w * w3v.y;
                acc[i][2] += xv.x * w0.z + xv.y * w1v.z + xv.z * w2v.z + xv.w * w3v.z;
                acc[i][3] += xv.x * w0.w + xv.y * w1v.w + xv.z * w2v.w + xv.w * w3v.w;
            }
        }
        __syncthreads();
    }

    const float4 b2v = ((const float4*)b2)[c];
    #pragma unroll
    for (int i = 0; i < 8; ++i) {
        int grow = row0 + g * 8 + i;
        if (grow < N_NODES) {
            float4 o;
            o.x = acc[i][0] + b2v.x;
            o.y = acc[i][1] + b2v.y;
            o.z = acc[i][2] + b2v.z;
            o.w = acc[i][3] + b2v.w;
            ((float4*)(out + (size_t)grow * C_OUT))[c] = o;
        }
    }
}

// ---------------------------------------------------------------------------
extern "C" void kernel_launch(void* const* d_in, const int* in_sizes, int n_in,
                              void* d_out, int out_size, void* d_ws, size_t ws_size,
                              hipStream_t stream)
{
    const float* x     = (const float*)d_in[0];
    // d_in[1] (x_struct), d_in[2] (x_e): unused by forward
    const int*   ei    = (const int*)d_in[3];   // [2, E] row-major int32
    const float* W1    = (const float*)d_in[4];
    const float* b1    = (const float*)d_in[5];
    const float* gamma = (const float*)d_in[6];
    const float* beta  = (const float*)d_in[7];
    const float* W2    = (const float*)d_in[8];
    const float* b2    = (const float*)d_in[9];
    float*       out   = (float*)d_out;

    // ws layout: h [N*128 f32] | agg [N*128 orderable-int]  = 102.4 MB
    float* h   = (float*)d_ws;
    int*   agg = (int*)d_ws + (size_t)N_NODES * C_HID;

    const int grid_gemm = (N_NODES + TILE_M - 1) / TILE_M;  // 1563

    init_agg_kernel<<<(N_NODES * C_HID / 4) / 256, 256, 0, stream>>>(agg);
    gemm1_ln_kernel<<<grid_gemm, 256, 0, stream>>>(x, W1, b1, gamma, beta, h);
    scatter_min_kernel<<<(N_EDGES * 32) / 256, 256, 0, stream>>>(ei, h, agg);
    gemm2_kernel<<<grid_gemm, 256, 0, stream>>>(agg, W2, b2, out);
}

// Round 2
// 762.872 us; speedup vs baseline: 1.1349x; 1.1349x over previous
//
#include <hip/hip_runtime.h>
#include <hip/hip_bf16.h>
#include <cstdint>

#define N_NODES 100000
#define N_EDGES 600000
#define C_IN    256
#define C_HID   128
#define C_OUT   128
#define LN_EPS  1e-5f
#define NEG_SLOPE 0.01f

#define TILE_M 64
#define KC     64   // K-chunk for gemm1
#define KC2    32   // K-chunk for fused gemm2 (keeps LDS < 50KB -> 3 blocks/CU)

#define NSCAN_BLOCKS 391  // ceil(100000/256)

// ---------------------------------------------------------------------------
// K_z: zero deg + cursor (2 * 100000 ints)
// ---------------------------------------------------------------------------
__global__ __launch_bounds__(256) void zero_kernel(int* __restrict__ p, int n) {
    int i = blockIdx.x * 256 + threadIdx.x;
    if (i < n) p[i] = 0;
}

// ---------------------------------------------------------------------------
// K_h: histogram of dst degrees
// ---------------------------------------------------------------------------
__global__ __launch_bounds__(256) void hist_kernel(const int* __restrict__ ei,
                                                   int* __restrict__ deg) {
    int t = blockIdx.x * 256 + threadIdx.x;
    if (t < N_EDGES) atomicAdd(&deg[ei[N_EDGES + t]], 1);
}

// ---------------------------------------------------------------------------
// K_s1: per-block sums of deg (256 elements/block)
// ---------------------------------------------------------------------------
__global__ __launch_bounds__(256) void block_sum_kernel(const int* __restrict__ deg,
                                                        int* __restrict__ bsum) {
    __shared__ int s[256];
    int i = blockIdx.x * 256 + threadIdx.x;
    s[threadIdx.x] = (i < N_NODES) ? deg[i] : 0;
    __syncthreads();
    #pragma unroll
    for (int o = 128; o > 0; o >>= 1) {
        if (threadIdx.x < o) s[threadIdx.x] += s[threadIdx.x + o];
        __syncthreads();
    }
    if (threadIdx.x == 0) bsum[blockIdx.x] = s[0];
}

// ---------------------------------------------------------------------------
// K_s2: single-block exclusive scan of the 391 block sums (Hillis-Steele)
// ---------------------------------------------------------------------------
__global__ __launch_bounds__(512) void scan_bsum_kernel(const int* __restrict__ bsum,
                                                        int* __restrict__ bpre,
                                                        int* __restrict__ offsets) {
    __shared__ int bufA[512], bufB[512];
    int t = threadIdx.x;
    int v = (t < NSCAN_BLOCKS) ? bsum[t] : 0;
    bufA[t] = v;
    __syncthreads();
    int* src = bufA; int* dst = bufB;
    #pragma unroll
    for (int o = 1; o < 512; o <<= 1) {
        dst[t] = src[t] + ((t >= o) ? src[t - o] : 0);
        __syncthreads();
        int* tmp = src; src = dst; dst = tmp;
    }
    if (t < NSCAN_BLOCKS) bpre[t] = src[t] - v;   // exclusive
    if (t == 0) offsets[N_NODES] = N_EDGES;
}

// ---------------------------------------------------------------------------
// K_s3: per-block exclusive scan + bpre -> global exclusive offsets
// ---------------------------------------------------------------------------
__global__ __launch_bounds__(256) void scan_block_kernel(const int* __restrict__ deg,
                                                         const int* __restrict__ bpre,
                                                         int* __restrict__ offsets) {
    __shared__ int bufA[256], bufB[256];
    int t = threadIdx.x;
    int i = blockIdx.x * 256 + t;
    int v = (i < N_NODES) ? deg[i] : 0;
    bufA[t] = v;
    __syncthreads();
    int* src = bufA; int* dst = bufB;
    #pragma unroll
    for (int o = 1; o < 256; o <<= 1) {
        dst[t] = src[t] + ((t >= o) ? src[t - o] : 0);
        __syncthreads();
        int* tmp = src; src = dst; dst = tmp;
    }
    if (i < N_NODES) offsets[i] = bpre[blockIdx.x] + src[t] - v;
}

// ---------------------------------------------------------------------------
// K_c: scatter edge srcs into CSR slots
// ---------------------------------------------------------------------------
__global__ __launch_bounds__(256) void csr_scatter_kernel(const int* __restrict__ ei,
                                                          const int* __restrict__ offsets,
                                                          int* __restrict__ cursor,
                                                          int* __restrict__ csr) {
    int t = blockIdx.x * 256 + threadIdx.x;
    if (t < N_EDGES) {
        int src = ei[t];
        int dst = ei[N_EDGES + t];
        int pos = atomicAdd(&cursor[dst], 1);
        csr[offsets[dst] + pos] = src;
    }
}

// ---------------------------------------------------------------------------
// K1: h = LayerNorm(LeakyReLU(x @ W1 + b1))  -> h [N, 128] fp32 in ws
// block 256 = 8 row-groups x 32 col-threads; each thread: 8 rows x 4 cols.
// ---------------------------------------------------------------------------
__global__ __launch_bounds__(256) void gemm1_ln_kernel(
    const float* __restrict__ x, const float* __restrict__ W1,
    const float* __restrict__ b1, const float* __restrict__ gamma,
    const float* __restrict__ beta, float* __restrict__ h)
{
    __shared__ float sW[KC][C_HID];       // 32 KB
    __shared__ float sX[TILE_M][KC + 4];  // 17 KB

    const int tid  = threadIdx.x;
    const int c    = tid & 31;
    const int g    = tid >> 5;
    const int row0 = blockIdx.x * TILE_M;

    float acc[8][4];
    #pragma unroll
    for (int i = 0; i < 8; ++i)
        #pragma unroll
        for (int j = 0; j < 4; ++j) acc[i][j] = 0.f;

    for (int k0 = 0; k0 < C_IN; k0 += KC) {
        #pragma unroll
        for (int l = 0; l < 8; ++l) {
            int idx = l * 256 + tid;
            int kk = idx >> 5, jj = idx & 31;
            ((float4*)&sW[kk][0])[jj] =
                ((const float4*)(W1 + (size_t)(k0 + kk) * C_HID))[jj];
        }
        #pragma unroll
        for (int l = 0; l < 4; ++l) {
            int idx = l * 256 + tid;
            int r = idx >> 4, q = idx & 15;
            int grow = row0 + r;
            float4 v = make_float4(0.f, 0.f, 0.f, 0.f);
            if (grow < N_NODES)
                v = ((const float4*)(x + (size_t)grow * C_IN + k0))[q];
            ((float4*)&sX[r][0])[q] = v;
        }
        __syncthreads();

        for (int kk = 0; kk < KC; kk += 4) {
            float4 w0 = ((const float4*)&sW[kk + 0][0])[c];
            float4 w1v = ((const float4*)&sW[kk + 1][0])[c];
            float4 w2v = ((const float4*)&sW[kk + 2][0])[c];
            float4 w3v = ((const float4*)&sW[kk + 3][0])[c];
            #pragma unroll
            for (int i = 0; i < 8; ++i) {
                float4 xv = *((const float4*)&sX[g * 8 + i][kk]);
                acc[i][0] += xv.x * w0.x + xv.y * w1v.x + xv.z * w2v.x + xv.w * w3v.x;
                acc[i][1] += xv.x * w0.y + xv.y * w1v.y + xv.z * w2v.y + xv.w * w3v.y;
                acc[i][2] += xv.x * w0.z + xv.y * w1v.z + xv.z * w2v.z + xv.w * w3v.z;
                acc[i][3] += xv.x * w0.w + xv.y * w1v.w + xv.z * w2v.w + xv.w * w3v.w;
            }
        }
        __syncthreads();
    }

    const float4 b1v = ((const float4*)b1)[c];
    const float4 gv  = ((const float4*)gamma)[c];
    const float4 bv  = ((const float4*)beta)[c];

    #pragma unroll
    for (int i = 0; i < 8; ++i) {
        int grow = row0 + g * 8 + i;
        float v0 = acc[i][0] + b1v.x;
        float v1 = acc[i][1] + b1v.y;
        float v2 = acc[i][2] + b1v.z;
        float v3 = acc[i][3] + b1v.w;
        v0 = (v0 > 0.f) ? v0 : NEG_SLOPE * v0;
        v1 = (v1 > 0.f) ? v1 : NEG_SLOPE * v1;
        v2 = (v2 > 0.f) ? v2 : NEG_SLOPE * v2;
        v3 = (v3 > 0.f) ? v3 : NEG_SLOPE * v3;
        float s  = v0 + v1 + v2 + v3;
        float ss = v0 * v0 + v1 * v1 + v2 * v2 + v3 * v3;
        #pragma unroll
        for (int m = 1; m < 32; m <<= 1) {
            s  += __shfl_xor(s, m, 32);
            ss += __shfl_xor(ss, m, 32);
        }
        float mu   = s * (1.f / C_HID);
        float var  = ss * (1.f / C_HID) - mu * mu;
        float rstd = rsqrtf(var + LN_EPS);
        float4 o;
        o.x = (v0 - mu) * rstd * gv.x + bv.x;
        o.y = (v1 - mu) * rstd * gv.y + bv.y;
        o.z = (v2 - mu) * rstd * gv.z + bv.z;
        o.w = (v3 - mu) * rstd * gv.w + bv.w;
        if (grow < N_NODES)
            ((float4*)(h + (size_t)grow * C_HID))[c] = o;
    }
}

// ---------------------------------------------------------------------------
// K2: fused CSR gather-min + GEMM2.
// Phase A: each of 4 waves computes exact fp32 min over incident edges for
//          16 rows (64 lanes x float2 per h-row, coalesced 512B), result in
//          sX[64][132] (empty nodes -> 0.0, matching PyG fill).
// Phase B: out_tile = sX @ W2 + b2, W2 staged in 32-row chunks (16KB).
// LDS total = 33.8 + 16 = 49.8 KB -> 3 blocks/CU.
// ---------------------------------------------------------------------------
__global__ __launch_bounds__(256) void agg_gemm2_kernel(
    const float* __restrict__ h, const int* __restrict__ offsets,
    const int* __restrict__ csr, const float* __restrict__ W2,
    const float* __restrict__ b2, float* __restrict__ out)
{
    __shared__ float sX[TILE_M][C_HID + 4];  // 64 x 132 floats
    __shared__ float sW[KC2][C_OUT];         // 32 x 128 floats

    const int tid  = threadIdx.x;
    const int row0 = blockIdx.x * TILE_M;

    // ---- Phase A: gather-min ----
    {
        const int lane = tid & 63;
        const int wv   = tid >> 6;          // 0..3
        for (int r = wv * 16; r < wv * 16 + 16; ++r) {
            int grow = row0 + r;
            float m0 = INFINITY, m1 = INFINITY;
            if (grow < N_NODES) {
                int beg = offsets[grow];
                int end = offsets[grow + 1];
                for (int j = beg; j < end; ++j) {
                    int s = csr[j];
                    float2 v = ((const float2*)(h + (size_t)s * C_HID))[lane];
                    m0 = fminf(m0, v.x);
                    m1 = fminf(m1, v.y);
                }
            }
            if (m0 == INFINITY) m0 = 0.f;    // empty segment -> 0 (h is finite)
            if (m1 == INFINITY) m1 = 0.f;
            sX[r][lane * 2 + 0] = m0;
            sX[r][lane * 2 + 1] = m1;
        }
    }
    __syncthreads();

    // ---- Phase B: GEMM ----
    const int c = tid & 31;
    const int g = tid >> 5;

    float acc[8][4];
    #pragma unroll
    for (int i = 0; i < 8; ++i)
        #pragma unroll
        for (int j = 0; j < 4; ++j) acc[i][j] = 0.f;

    for (int k0 = 0; k0 < C_HID; k0 += KC2) {
        // stage W2 chunk: 32x128 floats = 1024 float4, 4 per thread
        #pragma unroll
        for (int l = 0; l < 4; ++l) {
            int idx = l * 256 + tid;
            int kk = idx >> 5, jj = idx & 31;
            ((float4*)&sW[kk][0])[jj] =
                ((const float4*)(W2 + (size_t)(k0 + kk) * C_OUT))[jj];
        }
        __syncthreads();

        for (int kk = 0; kk < KC2; kk += 4) {
            float4 w0 = ((const float4*)&sW[kk + 0][0])[c];
            float4 w1v = ((const float4*)&sW[kk + 1][0])[c];
            float4 w2v = ((const float4*)&sW[kk + 2][0])[c];
            float4 w3v = ((const float4*)&sW[kk + 3][0])[c];
            #pragma unroll
            for (int i = 0; i < 8; ++i) {
                float4 xv = *((const float4*)&sX[g * 8 + i][k0 + kk]);
                acc[i][0] += xv.x * w0.x + xv.y * w1v.x + xv.z * w2v.x + xv.w * w3v.x;
                acc[i][1] += xv.x * w0.y + xv.y * w1v.y + xv.z * w2v.y + xv.w * w3v.y;
                acc[i][2] += xv.x * w0.z + xv.y * w1v.z + xv.z * w2v.z + xv.w * w3v.z;
                acc[i][3] += xv.x * w0.w + xv.y * w1v.w + xv.z * w2v.w + xv.w * w3v.w;
            }
        }
        __syncthreads();
    }

    const float4 b2v = ((const float4*)b2)[c];
    #pragma unroll
    for (int i = 0; i < 8; ++i) {
        int grow = row0 + g * 8 + i;
        if (grow < N_NODES) {
            float4 o;
            o.x = acc[i][0] + b2v.x;
            o.y = acc[i][1] + b2v.y;
            o.z = acc[i][2] + b2v.z;
            o.w = acc[i][3] + b2v.w;
            ((float4*)(out + (size_t)grow * C_OUT))[c] = o;
        }
    }
}

// ---------------------------------------------------------------------------
extern "C" void kernel_launch(void* const* d_in, const int* in_sizes, int n_in,
                              void* d_out, int out_size, void* d_ws, size_t ws_size,
                              hipStream_t stream)
{
    const float* x     = (const float*)d_in[0];
    const int*   ei    = (const int*)d_in[3];   // [2, E] row-major int32
    const float* W1    = (const float*)d_in[4];
    const float* b1    = (const float*)d_in[5];
    const float* gamma = (const float*)d_in[6];
    const float* beta  = (const float*)d_in[7];
    const float* W2    = (const float*)d_in[8];
    const float* b2    = (const float*)d_in[9];
    float*       out   = (float*)d_out;

    // ws layout (bytes): h 51.2MB | deg 0.4MB | cursor 0.4MB | offsets 0.4MB |
    //                    bsum | bpre | csr 2.4MB   (total ~54.5MB)
    char* p = (char*)d_ws;
    float* h       = (float*)p;            p += (size_t)N_NODES * C_HID * 4;
    int*   deg     = (int*)p;              p += 400000;
    int*   cursor  = (int*)p;              p += 400000;
    int*   offsets = (int*)p;              p += 400016;   // 100001 ints, padded
    int*   bsum    = (int*)p;              p += 1600;
    int*   bpre    = (int*)p;              p += 1600;
    int*   csr     = (int*)p;

    const int grid_e    = (N_EDGES + 255) / 256;    // 2344
    const int grid_gemm = (N_NODES + TILE_M - 1) / TILE_M;  // 1563

    zero_kernel<<<(2 * N_NODES + 255) / 256, 256, 0, stream>>>(deg, 2 * N_NODES);
    hist_kernel<<<grid_e, 256, 0, stream>>>(ei, deg);
    block_sum_kernel<<<NSCAN_BLOCKS, 256, 0, stream>>>(deg, bsum);
    scan_bsum_kernel<<<1, 512, 0, stream>>>(bsum, bpre, offsets);
    scan_block_kernel<<<NSCAN_BLOCKS, 256, 0, stream>>>(deg, bpre, offsets);
    csr_scatter_kernel<<<grid_e, 256, 0, stream>>>(ei, offsets, cursor, csr);
    gemm1_ln_kernel<<<grid_gemm, 256, 0, stream>>>(x, W1, b1, gamma, beta, h);
    agg_gemm2_kernel<<<grid_gemm, 256, 0, stream>>>(h, offsets, csr, W2, b2, out);
}

// Round 4
// 423.029 us; speedup vs baseline: 2.0467x; 1.8034x over previous
//
#include <hip/hip_runtime.h>
#include <hip/hip_bf16.h>
#include <cstdint>

#define N_NODES 100000
#define N_EDGES 600000
#define C_IN    256
#define C_HID   128
#define C_OUT   128
#define LN_EPS  1e-5f
#define NEG_SLOPE 0.01f

#define TILE_M 64
#define KC     64

#define NSCAN_BLOCKS 391  // ceil(100000/256)

// ---------------------------------------------------------------------------
// K_z: zero deg + cursor (2 * 100000 ints)
// ---------------------------------------------------------------------------
__global__ __launch_bounds__(256) void zero_kernel(int* __restrict__ p, int n) {
    int i = blockIdx.x * 256 + threadIdx.x;
    if (i < n) p[i] = 0;
}

// ---------------------------------------------------------------------------
// K_h: histogram of dst degrees
// ---------------------------------------------------------------------------
__global__ __launch_bounds__(256) void hist_kernel(const int* __restrict__ ei,
                                                   int* __restrict__ deg) {
    int t = blockIdx.x * 256 + threadIdx.x;
    if (t < N_EDGES) atomicAdd(&deg[ei[N_EDGES + t]], 1);
}

// ---------------------------------------------------------------------------
// K_s1: per-block sums of deg (256 elements/block)
// ---------------------------------------------------------------------------
__global__ __launch_bounds__(256) void block_sum_kernel(const int* __restrict__ deg,
                                                        int* __restrict__ bsum) {
    __shared__ int s[256];
    int i = blockIdx.x * 256 + threadIdx.x;
    s[threadIdx.x] = (i < N_NODES) ? deg[i] : 0;
    __syncthreads();
    #pragma unroll
    for (int o = 128; o > 0; o >>= 1) {
        if (threadIdx.x < o) s[threadIdx.x] += s[threadIdx.x + o];
        __syncthreads();
    }
    if (threadIdx.x == 0) bsum[blockIdx.x] = s[0];
}

// ---------------------------------------------------------------------------
// K_s2: single-block exclusive scan of the 391 block sums (Hillis-Steele)
// ---------------------------------------------------------------------------
__global__ __launch_bounds__(512) void scan_bsum_kernel(const int* __restrict__ bsum,
                                                        int* __restrict__ bpre,
                                                        int* __restrict__ offsets) {
    __shared__ int bufA[512], bufB[512];
    int t = threadIdx.x;
    int v = (t < NSCAN_BLOCKS) ? bsum[t] : 0;
    bufA[t] = v;
    __syncthreads();
    int* src = bufA; int* dst = bufB;
    #pragma unroll
    for (int o = 1; o < 512; o <<= 1) {
        dst[t] = src[t] + ((t >= o) ? src[t - o] : 0);
        __syncthreads();
        int* tmp = src; src = dst; dst = tmp;
    }
    if (t < NSCAN_BLOCKS) bpre[t] = src[t] - v;   // exclusive
    if (t == 0) offsets[N_NODES] = N_EDGES;
}

// ---------------------------------------------------------------------------
// K_s3: per-block exclusive scan + bpre -> global exclusive offsets
// ---------------------------------------------------------------------------
__global__ __launch_bounds__(256) void scan_block_kernel(const int* __restrict__ deg,
                                                         const int* __restrict__ bpre,
                                                         int* __restrict__ offsets) {
    __shared__ int bufA[256], bufB[256];
    int t = threadIdx.x;
    int i = blockIdx.x * 256 + t;
    int v = (i < N_NODES) ? deg[i] : 0;
    bufA[t] = v;
    __syncthreads();
    int* src = bufA; int* dst = bufB;
    #pragma unroll
    for (int o = 1; o < 256; o <<= 1) {
        dst[t] = src[t] + ((t >= o) ? src[t - o] : 0);
        __syncthreads();
        int* tmp = src; src = dst; dst = tmp;
    }
    if (i < N_NODES) offsets[i] = bpre[blockIdx.x] + src[t] - v;
}

// ---------------------------------------------------------------------------
// K_c: scatter edge srcs into CSR slots
// ---------------------------------------------------------------------------
__global__ __launch_bounds__(256) void csr_scatter_kernel(const int* __restrict__ ei,
                                                          const int* __restrict__ offsets,
                                                          int* __restrict__ cursor,
                                                          int* __restrict__ csr) {
    int t = blockIdx.x * 256 + threadIdx.x;
    if (t < N_EDGES) {
        int src = ei[t];
        int dst = ei[N_EDGES + t];
        int pos = atomicAdd(&cursor[dst], 1);
        csr[offsets[dst] + pos] = src;
    }
}

// ---------------------------------------------------------------------------
// K1: h = LayerNorm(LeakyReLU(x @ W1 + b1))  -> h [N, 128] fp32 in ws
// ---------------------------------------------------------------------------
__global__ __launch_bounds__(256) void gemm1_ln_kernel(
    const float* __restrict__ x, const float* __restrict__ W1,
    const float* __restrict__ b1, const float* __restrict__ gamma,
    const float* __restrict__ beta, float* __restrict__ h)
{
    __shared__ float sW[KC][C_HID];       // 32 KB
    __shared__ float sX[TILE_M][KC + 4];  // 17 KB

    const int tid  = threadIdx.x;
    const int c    = tid & 31;
    const int g    = tid >> 5;
    const int row0 = blockIdx.x * TILE_M;

    float acc[8][4];
    #pragma unroll
    for (int i = 0; i < 8; ++i)
        #pragma unroll
        for (int j = 0; j < 4; ++j) acc[i][j] = 0.f;

    for (int k0 = 0; k0 < C_IN; k0 += KC) {
        #pragma unroll
        for (int l = 0; l < 8; ++l) {
            int idx = l * 256 + tid;
            int kk = idx >> 5, jj = idx & 31;
            ((float4*)&sW[kk][0])[jj] =
                ((const float4*)(W1 + (size_t)(k0 + kk) * C_HID))[jj];
        }
        #pragma unroll
        for (int l = 0; l < 4; ++l) {
            int idx = l * 256 + tid;
            int r = idx >> 4, q = idx & 15;
            int grow = row0 + r;
            float4 v = make_float4(0.f, 0.f, 0.f, 0.f);
            if (grow < N_NODES)
                v = ((const float4*)(x + (size_t)grow * C_IN + k0))[q];
            ((float4*)&sX[r][0])[q] = v;
        }
        __syncthreads();

        for (int kk = 0; kk < KC; kk += 4) {
            float4 w0 = ((const float4*)&sW[kk + 0][0])[c];
            float4 w1v = ((const float4*)&sW[kk + 1][0])[c];
            float4 w2v = ((const float4*)&sW[kk + 2][0])[c];
            float4 w3v = ((const float4*)&sW[kk + 3][0])[c];
            #pragma unroll
            for (int i = 0; i < 8; ++i) {
                float4 xv = *((const float4*)&sX[g * 8 + i][kk]);
                acc[i][0] += xv.x * w0.x + xv.y * w1v.x + xv.z * w2v.x + xv.w * w3v.x;
                acc[i][1] += xv.x * w0.y + xv.y * w1v.y + xv.z * w2v.y + xv.w * w3v.y;
                acc[i][2] += xv.x * w0.z + xv.y * w1v.z + xv.z * w2v.z + xv.w * w3v.z;
                acc[i][3] += xv.x * w0.w + xv.y * w1v.w + xv.z * w2v.w + xv.w * w3v.w;
            }
        }
        __syncthreads();
    }

    const float4 b1v = ((const float4*)b1)[c];
    const float4 gv  = ((const float4*)gamma)[c];
    const float4 bv  = ((const float4*)beta)[c];

    #pragma unroll
    for (int i = 0; i < 8; ++i) {
        int grow = row0 + g * 8 + i;
        float v0 = acc[i][0] + b1v.x;
        float v1 = acc[i][1] + b1v.y;
        float v2 = acc[i][2] + b1v.z;
        float v3 = acc[i][3] + b1v.w;
        v0 = (v0 > 0.f) ? v0 : NEG_SLOPE * v0;
        v1 = (v1 > 0.f) ? v1 : NEG_SLOPE * v1;
        v2 = (v2 > 0.f) ? v2 : NEG_SLOPE * v2;
        v3 = (v3 > 0.f) ? v3 : NEG_SLOPE * v3;
        float s  = v0 + v1 + v2 + v3;
        float ss = v0 * v0 + v1 * v1 + v2 * v2 + v3 * v3;
        #pragma unroll
        for (int m = 1; m < 32; m <<= 1) {
            s  += __shfl_xor(s, m, 32);
            ss += __shfl_xor(ss, m, 32);
        }
        float mu   = s * (1.f / C_HID);
        float var  = ss * (1.f / C_HID) - mu * mu;
        float rstd = rsqrtf(var + LN_EPS);
        float4 o;
        o.x = (v0 - mu) * rstd * gv.x + bv.x;
        o.y = (v1 - mu) * rstd * gv.y + bv.y;
        o.z = (v2 - mu) * rstd * gv.z + bv.z;
        o.w = (v3 - mu) * rstd * gv.w + bv.w;
        if (grow < N_NODES)
            ((float4*)(h + (size_t)grow * C_HID))[c] = o;
    }
}

// ---------------------------------------------------------------------------
// K2: gather-min, ONE WAVE PER NODE (100k waves -> ~390/CU of TLP).
// CSR indices for the row are loaded cooperatively (one vector load per 64
// edges), distributed via __shfl -> the csr->h dependency leaves the chain.
// 4 independent h-row loads in flight per step; all branches wave-uniform.
// agg written as plain fp32 (no atomics anywhere).
// ---------------------------------------------------------------------------
__global__ __launch_bounds__(256) void gather_min_kernel(
    const float* __restrict__ h, const int* __restrict__ offsets,
    const int* __restrict__ csr, float* __restrict__ agg)
{
    const int lane = threadIdx.x & 63;
    const int row  = blockIdx.x * 4 + (threadIdx.x >> 6);
    if (row >= N_NODES) return;

    const int beg = offsets[row];
    const int end = offsets[row + 1];

    float m0 = INFINITY, m1 = INFINITY;

    for (int j0 = beg; j0 < end; j0 += 64) {
        const int cnt = min(64, end - j0);
        int idx = (lane < cnt) ? csr[j0 + lane] : 0;
        for (int k = 0; k < cnt; k += 4) {
            int s0 = __shfl(idx, k + 0);
            int s1 = __shfl(idx, k + 1);
            int s2 = __shfl(idx, k + 2);
            int s3 = __shfl(idx, k + 3);
            float2 v0 = ((const float2*)(h + (size_t)s0 * C_HID))[lane];
            float2 v1 = make_float2(INFINITY, INFINITY);
            float2 v2 = make_float2(INFINITY, INFINITY);
            float2 v3 = make_float2(INFINITY, INFINITY);
            if (k + 1 < cnt) v1 = ((const float2*)(h + (size_t)s1 * C_HID))[lane];
            if (k + 2 < cnt) v2 = ((const float2*)(h + (size_t)s2 * C_HID))[lane];
            if (k + 3 < cnt) v3 = ((const float2*)(h + (size_t)s3 * C_HID))[lane];
            m0 = fminf(fminf(m0, v0.x), fminf(fminf(v1.x, v2.x), v3.x));
            m1 = fminf(fminf(m1, v0.y), fminf(fminf(v1.y, v2.y), v3.y));
        }
    }

    if (m0 == INFINITY) m0 = 0.f;   // empty segment -> 0 (PyG fill; h is finite)
    if (m1 == INFINITY) m1 = 0.f;
    ((float2*)(agg + (size_t)row * C_HID))[lane] = make_float2(m0, m1);
}

// ---------------------------------------------------------------------------
// K3: out = agg @ W2 + b2   (plain fp32 GEMM, same tiling as K1, K=128)
// ---------------------------------------------------------------------------
__global__ __launch_bounds__(256) void gemm2_kernel(
    const float* __restrict__ agg, const float* __restrict__ W2,
    const float* __restrict__ b2, float* __restrict__ out)
{
    __shared__ float sW[KC][C_OUT];
    __shared__ float sX[TILE_M][KC + 4];

    const int tid  = threadIdx.x;
    const int c    = tid & 31;
    const int g    = tid >> 5;
    const int row0 = blockIdx.x * TILE_M;

    float acc[8][4];
    #pragma unroll
    for (int i = 0; i < 8; ++i)
        #pragma unroll
        for (int j = 0; j < 4; ++j) acc[i][j] = 0.f;

    for (int k0 = 0; k0 < C_HID; k0 += KC) {
        #pragma unroll
        for (int l = 0; l < 8; ++l) {
            int idx = l * 256 + tid;
            int kk = idx >> 5, jj = idx & 31;
            ((float4*)&sW[kk][0])[jj] =
                ((const float4*)(W2 + (size_t)(k0 + kk) * C_OUT))[jj];
        }
        #pragma unroll
        for (int l = 0; l < 4; ++l) {
            int idx = l * 256 + tid;
            int r = idx >> 4, q = idx & 15;
            int grow = row0 + r;
            float4 v = make_float4(0.f, 0.f, 0.f, 0.f);
            if (grow < N_NODES)
                v = ((const float4*)(agg + (size_t)grow * C_HID + k0))[q];
            ((float4*)&sX[r][0])[q] = v;
        }
        __syncthreads();

        for (int kk = 0; kk < KC; kk += 4) {
            float4 w0 = ((const float4*)&sW[kk + 0][0])[c];
            float4 w1v = ((const float4*)&sW[kk + 1][0])[c];
            float4 w2v = ((const float4*)&sW[kk + 2][0])[c];
            float4 w3v = ((const float4*)&sW[kk + 3][0])[c];
            #pragma unroll
            for (int i = 0; i < 8; ++i) {
                float4 xv = *((const float4*)&sX[g * 8 + i][kk]);
                acc[i][0] += xv.x * w0.x + xv.y * w1v.x + xv.z * w2v.x + xv.w * w3v.x;
                acc[i][1] += xv.x * w0.y + xv.y * w1v.y + xv.z * w2v.y + xv.w * w3v.y;
                acc[i][2] += xv.x * w0.z + xv.y * w1v.z + xv.z * w2v.z + xv.w * w3v.z;
                acc[i][3] += xv.x * w0.w + xv.y * w1v.w + xv.z * w2v.w + xv.w * w3v.w;
            }
        }
        __syncthreads();
    }

    const float4 b2v = ((const float4*)b2)[c];
    #pragma unroll
    for (int i = 0; i < 8; ++i) {
        int grow = row0 + g * 8 + i;
        if (grow < N_NODES) {
            float4 o;
            o.x = acc[i][0] + b2v.x;
            o.y = acc[i][1] + b2v.y;
            o.z = acc[i][2] + b2v.z;
            o.w = acc[i][3] + b2v.w;
            ((float4*)(out + (size_t)grow * C_OUT))[c] = o;
        }
    }
}

// ---------------------------------------------------------------------------
extern "C" void kernel_launch(void* const* d_in, const int* in_sizes, int n_in,
                              void* d_out, int out_size, void* d_ws, size_t ws_size,
                              hipStream_t stream)
{
    const float* x     = (const float*)d_in[0];
    const int*   ei    = (const int*)d_in[3];   // [2, E] row-major int32
    const float* W1    = (const float*)d_in[4];
    const float* b1    = (const float*)d_in[5];
    const float* gamma = (const float*)d_in[6];
    const float* beta  = (const float*)d_in[7];
    const float* W2    = (const float*)d_in[8];
    const float* b2    = (const float*)d_in[9];
    float*       out   = (float*)d_out;

    // ws layout: h 51.2MB | agg 51.2MB | deg | cursor | offsets | bsum | bpre | csr
    char* p = (char*)d_ws;
    float* h       = (float*)p;            p += (size_t)N_NODES * C_HID * 4;
    float* agg     = (float*)p;            p += (size_t)N_NODES * C_HID * 4;
    int*   deg     = (int*)p;              p += 400000;
    int*   cursor  = (int*)p;              p += 400000;
    int*   offsets = (int*)p;              p += 400016;   // 100001 ints, padded
    int*   bsum    = (int*)p;              p += 1600;
    int*   bpre    = (int*)p;              p += 1600;
    int*   csr     = (int*)p;

    const int grid_e    = (N_EDGES + 255) / 256;            // 2344
    const int grid_gemm = (N_NODES + TILE_M - 1) / TILE_M;  // 1563

    zero_kernel<<<(2 * N_NODES + 255) / 256, 256, 0, stream>>>(deg, 2 * N_NODES);
    hist_kernel<<<grid_e, 256, 0, stream>>>(ei, deg);
    block_sum_kernel<<<NSCAN_BLOCKS, 256, 0, stream>>>(deg, bsum);
    scan_bsum_kernel<<<1, 512, 0, stream>>>(bsum, bpre, offsets);
    scan_block_kernel<<<NSCAN_BLOCKS, 256, 0, stream>>>(deg, bpre, offsets);
    csr_scatter_kernel<<<grid_e, 256, 0, stream>>>(ei, offsets, cursor, csr);
    gemm1_ln_kernel<<<grid_gemm, 256, 0, stream>>>(x, W1, b1, gamma, beta, h);
    gather_min_kernel<<<(N_NODES + 3) / 4, 256, 0, stream>>>(h, offsets, csr, agg);
    gemm2_kernel<<<grid_gemm, 256, 0, stream>>>(agg, W2, b2, out);
}

// Round 5
// 354.416 us; speedup vs baseline: 2.4429x; 1.1936x over previous
//
#include <hip/hip_runtime.h>
#include <hip/hip_bf16.h>
#include <cstdint>

#define N_NODES 100000
#define N_EDGES 600000
#define C_IN    256
#define C_HID   128
#define C_OUT   128
#define LN_EPS  1e-5f
#define NEG_SLOPE 0.01f

#define NSCAN_BLOCKS 391  // ceil(100000/256)

typedef float f32x4 __attribute__((ext_vector_type(4)));
typedef __attribute__((ext_vector_type(8))) short frag_ab;  // 8 bf16 in 4 VGPRs

// ---- fp32 -> bf16 hi/lo split (RTZ hi, residual in lo; ~2^-16 rel total) ----
__device__ __forceinline__ void split2(float f, ushort& h, ushort& l) {
    unsigned u = __float_as_uint(f);
    h = (ushort)(u >> 16);
    float d = f - __uint_as_float(u & 0xFFFF0000u);
    l = (ushort)(__float_as_uint(d) >> 16);
}

__device__ __forceinline__ void split8(const float4& p, const float4& q,
                                       frag_ab& hi, frag_ab& lo) {
    ushort h, l;
    split2(p.x, h, l); hi[0] = (short)h; lo[0] = (short)l;
    split2(p.y, h, l); hi[1] = (short)h; lo[1] = (short)l;
    split2(p.z, h, l); hi[2] = (short)h; lo[2] = (short)l;
    split2(p.w, h, l); hi[3] = (short)h; lo[3] = (short)l;
    split2(q.x, h, l); hi[4] = (short)h; lo[4] = (short)l;
    split2(q.y, h, l); hi[5] = (short)h; lo[5] = (short)l;
    split2(q.z, h, l); hi[6] = (short)h; lo[6] = (short)l;
    split2(q.w, h, l); hi[7] = (short)h; lo[7] = (short)l;
}

// ---------------------------------------------------------------------------
// Stage a 128(k) x 128(n) fp32 W chunk into LDS as bf16 hi/lo, layout [n][k],
// XOR-swizzled (byte ^= (n&7)<<4) so B-frag ds_read_b128 is ~conflict-free.
// Global reads are 256B-coalesced (lanes sweep n); writes are ushort4 (8B).
// ---------------------------------------------------------------------------
__device__ __forceinline__ void stage_w_chunk(const float* __restrict__ Wk,
                                              ushort* __restrict__ sW, int tid) {
    #pragma unroll
    for (int it = 0; it < 16; ++it) {
        int id = it * 256 + tid;
        int n  = id & 127;
        int kg = id >> 7;            // 0..31 (4 k's each)
        float w0 = Wk[(kg * 4 + 0) * 128 + n];
        float w1 = Wk[(kg * 4 + 1) * 128 + n];
        float w2 = Wk[(kg * 4 + 2) * 128 + n];
        float w3 = Wk[(kg * 4 + 3) * 128 + n];
        ushort h0, h1, h2, h3, l0, l1, l2, l3;
        split2(w0, h0, l0); split2(w1, h1, l1);
        split2(w2, h2, l2); split2(w3, h3, l3);
        int bbyte = n * 256 + ((kg * 8) ^ ((n & 7) << 4));
        *(ushort4*)((char*)sW + bbyte)         = make_ushort4(h0, h1, h2, h3);
        *(ushort4*)((char*)sW + 65536 + bbyte) = make_ushort4(l0, l1, l2, l3);
    }
}

// ---------------------------------------------------------------------------
// K0..: CSR build chain (unchanged from R4)
// ---------------------------------------------------------------------------
__global__ __launch_bounds__(256) void zero_kernel(int* __restrict__ p, int n) {
    int i = blockIdx.x * 256 + threadIdx.x;
    if (i < n) p[i] = 0;
}

__global__ __launch_bounds__(256) void hist_kernel(const int* __restrict__ ei,
                                                   int* __restrict__ deg) {
    int t = blockIdx.x * 256 + threadIdx.x;
    if (t < N_EDGES) atomicAdd(&deg[ei[N_EDGES + t]], 1);
}

__global__ __launch_bounds__(256) void block_sum_kernel(const int* __restrict__ deg,
                                                        int* __restrict__ bsum) {
    __shared__ int s[256];
    int i = blockIdx.x * 256 + threadIdx.x;
    s[threadIdx.x] = (i < N_NODES) ? deg[i] : 0;
    __syncthreads();
    #pragma unroll
    for (int o = 128; o > 0; o >>= 1) {
        if (threadIdx.x < o) s[threadIdx.x] += s[threadIdx.x + o];
        __syncthreads();
    }
    if (threadIdx.x == 0) bsum[blockIdx.x] = s[0];
}

__global__ __launch_bounds__(512) void scan_bsum_kernel(const int* __restrict__ bsum,
                                                        int* __restrict__ bpre,
                                                        int* __restrict__ offsets) {
    __shared__ int bufA[512], bufB[512];
    int t = threadIdx.x;
    int v = (t < NSCAN_BLOCKS) ? bsum[t] : 0;
    bufA[t] = v;
    __syncthreads();
    int* src = bufA; int* dst = bufB;
    #pragma unroll
    for (int o = 1; o < 512; o <<= 1) {
        dst[t] = src[t] + ((t >= o) ? src[t - o] : 0);
        __syncthreads();
        int* tmp = src; src = dst; dst = tmp;
    }
    if (t < NSCAN_BLOCKS) bpre[t] = src[t] - v;   // exclusive
    if (t == 0) offsets[N_NODES] = N_EDGES;
}

__global__ __launch_bounds__(256) void scan_block_kernel(const int* __restrict__ deg,
                                                         const int* __restrict__ bpre,
                                                         int* __restrict__ offsets) {
    __shared__ int bufA[256], bufB[256];
    int t = threadIdx.x;
    int i = blockIdx.x * 256 + t;
    int v = (i < N_NODES) ? deg[i] : 0;
    bufA[t] = v;
    __syncthreads();
    int* src = bufA; int* dst = bufB;
    #pragma unroll
    for (int o = 1; o < 256; o <<= 1) {
        dst[t] = src[t] + ((t >= o) ? src[t - o] : 0);
        __syncthreads();
        int* tmp = src; src = dst; dst = tmp;
    }
    if (i < N_NODES) offsets[i] = bpre[blockIdx.x] + src[t] - v;
}

__global__ __launch_bounds__(256) void csr_scatter_kernel(const int* __restrict__ ei,
                                                          const int* __restrict__ offsets,
                                                          int* __restrict__ cursor,
                                                          int* __restrict__ csr) {
    int t = blockIdx.x * 256 + threadIdx.x;
    if (t < N_EDGES) {
        int src = ei[t];
        int dst = ei[N_EDGES + t];
        int pos = atomicAdd(&cursor[dst], 1);
        csr[offsets[dst] + pos] = src;
    }
}

// ---------------------------------------------------------------------------
// K1: h = LN(LeakyReLU(x @ W1 + b1)) via 3-term bf16-split MFMA.
// Block 256 = 4 waves x 32 rows (BM=128). K=256 in two 128-chunks.
// A: direct-from-global (16 rows x 128B coalesced segments), reg-prefetched
//    per chunk so W-staging hides the latency. W: LDS [n][k] hi/lo, swizzled.
// MFMA 16x16x32 bf16; C/D: col=lane&15, row=(lane>>4)*4+reg.
// ---------------------------------------------------------------------------
__global__ __launch_bounds__(256, 2) void gemm1_ln_mfma_kernel(
    const float* __restrict__ x, const float* __restrict__ W1,
    const float* __restrict__ b1, const float* __restrict__ gamma,
    const float* __restrict__ beta, float* __restrict__ h)
{
    __shared__ ushort sW[2 * 128 * 128];   // hi [0,32768), lo [32768,65536) : 64KB

    const int tid  = threadIdx.x;
    const int lane = tid & 63;
    const int wv   = tid >> 6;          // wave id 0..3
    const int r16  = lane & 15;
    const int g    = lane >> 4;         // 0..3
    const int row0 = blockIdx.x * 128;

    f32x4 acc[2][8];
    #pragma unroll
    for (int mf = 0; mf < 2; ++mf)
        #pragma unroll
        for (int nf = 0; nf < 8; ++nf)
            acc[mf][nf] = (f32x4){0.f, 0.f, 0.f, 0.f};

    // per-lane epilogue params (cols nf*16 + r16)
    float b1v[8], gv[8], bv[8];
    #pragma unroll
    for (int nf = 0; nf < 8; ++nf) {
        int cidx = nf * 16 + r16;
        b1v[nf] = b1[cidx]; gv[nf] = gamma[cidx]; bv[nf] = beta[cidx];
    }

    const char* bbase = (const char*)sW + r16 * 256;
    const int swz = (lane & 7) << 4;

    for (int kc = 0; kc < 2; ++kc) {
        // prefetch this chunk's A rows (raw fp32) — 16 x dwordx4
        float4 araw[2][4][2];
        #pragma unroll
        for (int mf = 0; mf < 2; ++mf) {
            int r_a = row0 + wv * 32 + mf * 16 + r16;
            r_a = (r_a < N_NODES) ? r_a : (N_NODES - 1);
            const float* xp = x + (size_t)r_a * C_IN + kc * 128 + g * 8;
            #pragma unroll
            for (int ks = 0; ks < 4; ++ks) {
                araw[mf][ks][0] = *(const float4*)(xp + ks * 32);
                araw[mf][ks][1] = *(const float4*)(xp + ks * 32 + 4);
            }
        }

        stage_w_chunk(W1 + (size_t)kc * 128 * 128, sW, tid);
        __syncthreads();

        #pragma unroll
        for (int ks = 0; ks < 4; ++ks) {
            frag_ab aHi[2], aLo[2];
            split8(araw[0][ks][0], araw[0][ks][1], aHi[0], aLo[0]);
            split8(araw[1][ks][0], araw[1][ks][1], aHi[1], aLo[1]);
            const int kpart = (ks * 64 + g * 16) ^ swz;
            #pragma unroll
            for (int nf = 0; nf < 8; ++nf) {
                frag_ab bHi = *(const frag_ab*)(bbase + nf * 4096 + kpart);
                frag_ab bLo = *(const frag_ab*)(bbase + nf * 4096 + kpart + 65536);
                acc[0][nf] = __builtin_amdgcn_mfma_f32_16x16x32_bf16(aHi[0], bHi, acc[0][nf], 0, 0, 0);
                acc[0][nf] = __builtin_amdgcn_mfma_f32_16x16x32_bf16(aLo[0], bHi, acc[0][nf], 0, 0, 0);
                acc[0][nf] = __builtin_amdgcn_mfma_f32_16x16x32_bf16(aHi[0], bLo, acc[0][nf], 0, 0, 0);
                acc[1][nf] = __builtin_amdgcn_mfma_f32_16x16x32_bf16(aHi[1], bHi, acc[1][nf], 0, 0, 0);
                acc[1][nf] = __builtin_amdgcn_mfma_f32_16x16x32_bf16(aLo[1], bHi, acc[1][nf], 0, 0, 0);
                acc[1][nf] = __builtin_amdgcn_mfma_f32_16x16x32_bf16(aHi[1], bLo, acc[1][nf], 0, 0, 0);
            }
        }
        __syncthreads();
    }

    // ---- epilogue: +b1, LeakyReLU, LayerNorm, store h ----
    #pragma unroll
    for (int mf = 0; mf < 2; ++mf)
        #pragma unroll
        for (int nf = 0; nf < 8; ++nf)
            #pragma unroll
            for (int rg = 0; rg < 4; ++rg) {
                float v = acc[mf][nf][rg] + b1v[nf];
                acc[mf][nf][rg] = (v > 0.f) ? v : NEG_SLOPE * v;
            }

    #pragma unroll
    for (int mf = 0; mf < 2; ++mf) {
        #pragma unroll
        for (int rg = 0; rg < 4; ++rg) {
            float s = 0.f, ss = 0.f;
            #pragma unroll
            for (int nf = 0; nf < 8; ++nf) {
                float v = acc[mf][nf][rg];
                s += v; ss += v * v;
            }
            // reduce across the 16 lanes holding this row (low-4 lane bits)
            #pragma unroll
            for (int m = 1; m < 16; m <<= 1) {
                s  += __shfl_xor(s,  m, 64);
                ss += __shfl_xor(ss, m, 64);
            }
            float mu   = s * (1.f / C_HID);
            float var  = ss * (1.f / C_HID) - mu * mu;
            float rstd = rsqrtf(var + LN_EPS);
            int row = row0 + wv * 32 + mf * 16 + (g << 2) + rg;
            if (row < N_NODES) {
                #pragma unroll
                for (int nf = 0; nf < 8; ++nf) {
                    float o = (acc[mf][nf][rg] - mu) * rstd * gv[nf] + bv[nf];
                    h[(size_t)row * C_HID + nf * 16 + r16] = o;
                }
            }
        }
    }
}

// ---------------------------------------------------------------------------
// K2: gather-min, one wave per node (unchanged from R4).
// ---------------------------------------------------------------------------
__global__ __launch_bounds__(256) void gather_min_kernel(
    const float* __restrict__ h, const int* __restrict__ offsets,
    const int* __restrict__ csr, float* __restrict__ agg)
{
    const int lane = threadIdx.x & 63;
    const int row  = blockIdx.x * 4 + (threadIdx.x >> 6);
    if (row >= N_NODES) return;

    const int beg = offsets[row];
    const int end = offsets[row + 1];

    float m0 = INFINITY, m1 = INFINITY;

    for (int j0 = beg; j0 < end; j0 += 64) {
        const int cnt = min(64, end - j0);
        int idx = (lane < cnt) ? csr[j0 + lane] : 0;
        for (int k = 0; k < cnt; k += 4) {
            int s0 = __shfl(idx, k + 0);
            int s1 = __shfl(idx, k + 1);
            int s2 = __shfl(idx, k + 2);
            int s3 = __shfl(idx, k + 3);
            float2 v0 = ((const float2*)(h + (size_t)s0 * C_HID))[lane];
            float2 v1 = make_float2(INFINITY, INFINITY);
            float2 v2 = make_float2(INFINITY, INFINITY);
            float2 v3 = make_float2(INFINITY, INFINITY);
            if (k + 1 < cnt) v1 = ((const float2*)(h + (size_t)s1 * C_HID))[lane];
            if (k + 2 < cnt) v2 = ((const float2*)(h + (size_t)s2 * C_HID))[lane];
            if (k + 3 < cnt) v3 = ((const float2*)(h + (size_t)s3 * C_HID))[lane];
            m0 = fminf(fminf(m0, v0.x), fminf(fminf(v1.x, v2.x), v3.x));
            m1 = fminf(fminf(m1, v0.y), fminf(fminf(v1.y, v2.y), v3.y));
        }
    }

    if (m0 == INFINITY) m0 = 0.f;   // empty segment -> 0 (PyG fill; h is finite)
    if (m1 == INFINITY) m1 = 0.f;
    ((float2*)(agg + (size_t)row * C_HID))[lane] = make_float2(m0, m1);
}

// ---------------------------------------------------------------------------
// K3: out = agg @ W2 + b2 via 3-term bf16-split MFMA (K=128, one chunk).
// ---------------------------------------------------------------------------
__global__ __launch_bounds__(256, 2) void gemm2_mfma_kernel(
    const float* __restrict__ agg, const float* __restrict__ W2,
    const float* __restrict__ b2, float* __restrict__ out)
{
    __shared__ ushort sW[2 * 128 * 128];

    const int tid  = threadIdx.x;
    const int lane = tid & 63;
    const int wv   = tid >> 6;
    const int r16  = lane & 15;
    const int g    = lane >> 4;
    const int row0 = blockIdx.x * 128;

    f32x4 acc[2][8];
    #pragma unroll
    for (int mf = 0; mf < 2; ++mf)
        #pragma unroll
        for (int nf = 0; nf < 8; ++nf)
            acc[mf][nf] = (f32x4){0.f, 0.f, 0.f, 0.f};

    float b2v[8];
    #pragma unroll
    for (int nf = 0; nf < 8; ++nf) b2v[nf] = b2[nf * 16 + r16];

    // prefetch A (agg rows, K=128)
    float4 araw[2][4][2];
    #pragma unroll
    for (int mf = 0; mf < 2; ++mf) {
        int r_a = row0 + wv * 32 + mf * 16 + r16;
        r_a = (r_a < N_NODES) ? r_a : (N_NODES - 1);
        const float* ap = agg + (size_t)r_a * C_HID + g * 8;
        #pragma unroll
        for (int ks = 0; ks < 4; ++ks) {
            araw[mf][ks][0] = *(const float4*)(ap + ks * 32);
            araw[mf][ks][1] = *(const float4*)(ap + ks * 32 + 4);
        }
    }

    stage_w_chunk(W2, sW, tid);
    __syncthreads();

    const char* bbase = (const char*)sW + r16 * 256;
    const int swz = (lane & 7) << 4;

    #pragma unroll
    for (int ks = 0; ks < 4; ++ks) {
        frag_ab aHi[2], aLo[2];
        split8(araw[0][ks][0], araw[0][ks][1], aHi[0], aLo[0]);
        split8(araw[1][ks][0], araw[1][ks][1], aHi[1], aLo[1]);
        const int kpart = (ks * 64 + g * 16) ^ swz;
        #pragma unroll
        for (int nf = 0; nf < 8; ++nf) {
            frag_ab bHi = *(const frag_ab*)(bbase + nf * 4096 + kpart);
            frag_ab bLo = *(const frag_ab*)(bbase + nf * 4096 + kpart + 65536);
            acc[0][nf] = __builtin_amdgcn_mfma_f32_16x16x32_bf16(aHi[0], bHi, acc[0][nf], 0, 0, 0);
            acc[0][nf] = __builtin_amdgcn_mfma_f32_16x16x32_bf16(aLo[0], bHi, acc[0][nf], 0, 0, 0);
            acc[0][nf] = __builtin_amdgcn_mfma_f32_16x16x32_bf16(aHi[0], bLo, acc[0][nf], 0, 0, 0);
            acc[1][nf] = __builtin_amdgcn_mfma_f32_16x16x32_bf16(aHi[1], bHi, acc[1][nf], 0, 0, 0);
            acc[1][nf] = __builtin_amdgcn_mfma_f32_16x16x32_bf16(aLo[1], bHi, acc[1][nf], 0, 0, 0);
            acc[1][nf] = __builtin_amdgcn_mfma_f32_16x16x32_bf16(aHi[1], bLo, acc[1][nf], 0, 0, 0);
        }
    }

    #pragma unroll
    for (int mf = 0; mf < 2; ++mf) {
        #pragma unroll
        for (int rg = 0; rg < 4; ++rg) {
            int row = row0 + wv * 32 + mf * 16 + (g << 2) + rg;
            if (row < N_NODES) {
                #pragma unroll
                for (int nf = 0; nf < 8; ++nf)
                    out[(size_t)row * C_OUT + nf * 16 + r16] = acc[mf][nf][rg] + b2v[nf];
            }
        }
    }
}

// ---------------------------------------------------------------------------
extern "C" void kernel_launch(void* const* d_in, const int* in_sizes, int n_in,
                              void* d_out, int out_size, void* d_ws, size_t ws_size,
                              hipStream_t stream)
{
    const float* x     = (const float*)d_in[0];
    const int*   ei    = (const int*)d_in[3];   // [2, E] row-major int32
    const float* W1    = (const float*)d_in[4];
    const float* b1    = (const float*)d_in[5];
    const float* gamma = (const float*)d_in[6];
    const float* beta  = (const float*)d_in[7];
    const float* W2    = (const float*)d_in[8];
    const float* b2    = (const float*)d_in[9];
    float*       out   = (float*)d_out;

    // ws layout: h 51.2MB | agg 51.2MB | deg | cursor | offsets | bsum | bpre | csr
    char* p = (char*)d_ws;
    float* h       = (float*)p;            p += (size_t)N_NODES * C_HID * 4;
    float* agg     = (float*)p;            p += (size_t)N_NODES * C_HID * 4;
    int*   deg     = (int*)p;              p += 400000;
    int*   cursor  = (int*)p;              p += 400000;
    int*   offsets = (int*)p;              p += 400016;   // 100001 ints, padded
    int*   bsum    = (int*)p;              p += 1600;
    int*   bpre    = (int*)p;              p += 1600;
    int*   csr     = (int*)p;

    const int grid_e    = (N_EDGES + 255) / 256;   // 2344
    const int grid_gemm = (N_NODES + 127) / 128;   // 782

    zero_kernel<<<(2 * N_NODES + 255) / 256, 256, 0, stream>>>(deg, 2 * N_NODES);
    hist_kernel<<<grid_e, 256, 0, stream>>>(ei, deg);
    block_sum_kernel<<<NSCAN_BLOCKS, 256, 0, stream>>>(deg, bsum);
    scan_bsum_kernel<<<1, 512, 0, stream>>>(bsum, bpre, offsets);
    scan_block_kernel<<<NSCAN_BLOCKS, 256, 0, stream>>>(deg, bpre, offsets);
    csr_scatter_kernel<<<grid_e, 256, 0, stream>>>(ei, offsets, cursor, csr);
    gemm1_ln_mfma_kernel<<<grid_gemm, 256, 0, stream>>>(x, W1, b1, gamma, beta, h);
    gather_min_kernel<<<(N_NODES + 3) / 4, 256, 0, stream>>>(h, offsets, csr, agg);
    gemm2_mfma_kernel<<<grid_gemm, 256, 0, stream>>>(agg, W2, b2, out);
}